// Round 1
// baseline (403.436 us; speedup 1.0000x reference)
//
#include <hip/hip_runtime.h>
#include <math.h>

// ---------------------------------------------------------------------------
// Only sample 0 of the batch affects the loss (features[0], cap[0]).
// Pipeline (all fp32):
//   K1 conv1(3->4)+relu+pool  : img0 -> p1[4][256][256]
//   K2 conv2(4->16)+relu+pool : p1   -> xf[16][128][128]
//   K3 fused NetVLAD softmax+accumulate -> vacc[64][16], asum[64]
//   K4 vlad normalize (intra+global) + FC -> feat[512]
//   K5 U[t] = hid_w[:, :300] @ cap0[t] + hid_b   (t = 0..62)
//   K6 sequential RNN: h <- sigmoid(W_h h + U[t]); W_h pinned in VGPRs of
//      8 co-resident blocks; global one-shot counter barrier per step
//   K7 y_t = sigmoid(out_w @ h_t + out_b); loss = mean((out-cap0)^2)
// ---------------------------------------------------------------------------

__device__ __forceinline__ float sigmoidf_(float x) {
  return 1.0f / (1.0f + __expf(-x));
}

// K1: conv1 + relu + avgpool2. grid 1024x256, one thread per pooled output.
__global__ __launch_bounds__(256) void k_conv1(const float* __restrict__ img,
                                               const float* __restrict__ w,
                                               const float* __restrict__ b,
                                               float* __restrict__ p1) {
  int idx = blockIdx.x * 256 + threadIdx.x;
  int ox = idx & 255;
  int oy = (idx >> 8) & 255;
  int c  = idx >> 16;                 // block-uniform (65536 per channel)
  __shared__ float wsh[27];
  __shared__ float bsh;
  if (threadIdx.x < 27) wsh[threadIdx.x] = w[c * 27 + threadIdx.x];
  if (threadIdx.x == 0) bsh = b[c];
  __syncthreads();
  int y0 = oy * 2 - 1, x0 = ox * 2 - 1;
  float a00, a01, a10, a11;
  a00 = a01 = a10 = a11 = bsh;
  #pragma unroll
  for (int ci = 0; ci < 3; ++ci) {
    float P[4][4];
    #pragma unroll
    for (int j = 0; j < 4; ++j) {
      int y = y0 + j;
      #pragma unroll
      for (int i = 0; i < 4; ++i) {
        int x = x0 + i;
        bool ok = ((unsigned)y < 512u) && ((unsigned)x < 512u);
        P[j][i] = ok ? img[ci * 262144 + y * 512 + x] : 0.0f;
      }
    }
    #pragma unroll
    for (int ky = 0; ky < 3; ++ky) {
      #pragma unroll
      for (int kx = 0; kx < 3; ++kx) {
        float wv = wsh[ci * 9 + ky * 3 + kx];
        a00 = fmaf(wv, P[ky][kx],         a00);
        a01 = fmaf(wv, P[ky][kx + 1],     a01);
        a10 = fmaf(wv, P[ky + 1][kx],     a10);
        a11 = fmaf(wv, P[ky + 1][kx + 1], a11);
      }
    }
  }
  p1[idx] = 0.25f * (fmaxf(a00, 0.f) + fmaxf(a01, 0.f) +
                     fmaxf(a10, 0.f) + fmaxf(a11, 0.f));
}

// K2: conv2 + relu + avgpool2. grid 1024x256.
__global__ __launch_bounds__(256) void k_conv2(const float* __restrict__ p1,
                                               const float* __restrict__ w,
                                               const float* __restrict__ b,
                                               float* __restrict__ xf) {
  int idx = blockIdx.x * 256 + threadIdx.x;
  int ox = idx & 127;
  int oy = (idx >> 7) & 127;
  int c  = idx >> 14;                 // block-uniform (16384 per channel)
  __shared__ float wsh[36];
  __shared__ float bsh;
  if (threadIdx.x < 36) wsh[threadIdx.x] = w[c * 36 + threadIdx.x];
  if (threadIdx.x == 0) bsh = b[c];
  __syncthreads();
  int y0 = oy * 2 - 1, x0 = ox * 2 - 1;
  float a00, a01, a10, a11;
  a00 = a01 = a10 = a11 = bsh;
  #pragma unroll
  for (int ci = 0; ci < 4; ++ci) {
    float P[4][4];
    #pragma unroll
    for (int j = 0; j < 4; ++j) {
      int y = y0 + j;
      #pragma unroll
      for (int i = 0; i < 4; ++i) {
        int x = x0 + i;
        bool ok = ((unsigned)y < 256u) && ((unsigned)x < 256u);
        P[j][i] = ok ? p1[ci * 65536 + y * 256 + x] : 0.0f;
      }
    }
    #pragma unroll
    for (int ky = 0; ky < 3; ++ky) {
      #pragma unroll
      for (int kx = 0; kx < 3; ++kx) {
        float wv = wsh[ci * 9 + ky * 3 + kx];
        a00 = fmaf(wv, P[ky][kx],         a00);
        a01 = fmaf(wv, P[ky][kx + 1],     a01);
        a10 = fmaf(wv, P[ky + 1][kx],     a10);
        a11 = fmaf(wv, P[ky + 1][kx + 1], a11);
      }
    }
  }
  xf[idx] = 0.25f * (fmaxf(a00, 0.f) + fmaxf(a01, 0.f) +
                     fmaxf(a10, 0.f) + fmaxf(a11, 0.f));
}

// K3: NetVLAD fused logits+softmax+accumulate. grid 64x256, thread = 1 hw pos.
#define PS_STRIDE 65
#define XS_STRIDE 20
__global__ __launch_bounds__(256, 1) void k_netvlad(const float* __restrict__ xf,
                                                    const float* __restrict__ nvw,
                                                    const float* __restrict__ nvb,
                                                    float* __restrict__ vacc,
                                                    float* __restrict__ asum) {
  __shared__ __align__(16) float ps[128 * PS_STRIDE];  // 33.3 KB
  __shared__ __align__(16) float xs[128 * XS_STRIDE];  // 10.2 KB
  __shared__ float wsh[1024];
  __shared__ float bsh[64];
  __shared__ float aS[256];
  int tid = threadIdx.x;
  for (int i = tid; i < 1024; i += 256) wsh[i] = nvw[i];
  if (tid < 64) bsh[tid] = nvb[tid];
  __syncthreads();

  int hw = blockIdx.x * 256 + tid;
  float x[16];
  #pragma unroll
  for (int c = 0; c < 16; ++c) x[c] = xf[c * 16384 + hw];

  float p[64];
  float m = -1e30f;
  #pragma unroll
  for (int k = 0; k < 64; ++k) {
    float acc = bsh[k];
    #pragma unroll
    for (int c = 0; c < 16; ++c) acc = fmaf(wsh[k * 16 + c], x[c], acc);
    p[k] = acc;
    m = fmaxf(m, acc);
  }
  float s = 0.f;
  #pragma unroll
  for (int k = 0; k < 64; ++k) { p[k] = __expf(p[k] - m); s += p[k]; }
  float inv = 1.0f / s;
  #pragma unroll
  for (int k = 0; k < 64; ++k) p[k] *= inv;

  int q = tid >> 6, k = tid & 63;
  float acc[16];
  #pragma unroll
  for (int c = 0; c < 16; ++c) acc[c] = 0.f;
  float accA = 0.f;

  // Two staging passes of 128 hw positions each (fits 64 KB LDS budget).
  for (int pass = 0; pass < 2; ++pass) {
    __syncthreads();
    if ((tid >> 7) == pass) {
      int tt = tid & 127;
      #pragma unroll
      for (int kk = 0; kk < 64; ++kk) ps[tt * PS_STRIDE + kk] = p[kk];
      #pragma unroll
      for (int c = 0; c < 16; ++c) xs[tt * XS_STRIDE + c] = x[c];
    }
    __syncthreads();
    #pragma unroll
    for (int j = 0; j < 32; ++j) {
      int tt = q * 32 + j;
      float pv = ps[tt * PS_STRIDE + k];
      accA += pv;
      const float4* xv = (const float4*)(xs + tt * XS_STRIDE);
      #pragma unroll
      for (int c4 = 0; c4 < 4; ++c4) {
        float4 xx = xv[c4];
        acc[c4 * 4 + 0] = fmaf(pv, xx.x, acc[c4 * 4 + 0]);
        acc[c4 * 4 + 1] = fmaf(pv, xx.y, acc[c4 * 4 + 1]);
        acc[c4 * 4 + 2] = fmaf(pv, xx.z, acc[c4 * 4 + 2]);
        acc[c4 * 4 + 3] = fmaf(pv, xx.w, acc[c4 * 4 + 3]);
      }
    }
  }
  __syncthreads();
  // cross-wave (q) reduction, reuse ps as [256][16] scratch
  float* red = ps;
  #pragma unroll
  for (int c = 0; c < 16; ++c) red[tid * 16 + c] = acc[c];
  aS[tid] = accA;
  __syncthreads();
  if (q == 0) {
    float a = aS[k] + aS[64 + k] + aS[128 + k] + aS[192 + k];
    atomicAdd(&asum[k], a);
  }
  int k2 = tid >> 2;
  int cg = (tid & 3) * 4;
  #pragma unroll
  for (int cc = 0; cc < 4; ++cc) {
    int c = cg + cc;
    float v = red[(0 * 64 + k2) * 16 + c] + red[(1 * 64 + k2) * 16 + c] +
              red[(2 * 64 + k2) * 16 + c] + red[(3 * 64 + k2) * 16 + c];
    atomicAdd(&vacc[k2 * 16 + c], v);
  }
}

// K4: vlad finalize (subtract, intra-norm, global-norm) + FC. 1 block x 512.
__global__ __launch_bounds__(512) void k_vlad_fc(const float* __restrict__ vacc,
                                                 const float* __restrict__ asum,
                                                 const float* __restrict__ cent,
                                                 const float* __restrict__ fcw,
                                                 const float* __restrict__ fcb,
                                                 float* __restrict__ feat) {
  __shared__ __align__(16) float v[1024];
  __shared__ float rn[64];
  __shared__ float red[9];
  int tid = threadIdx.x;
  for (int i = tid; i < 1024; i += 512)
    v[i] = vacc[i] - asum[i >> 4] * cent[i];
  __syncthreads();
  if (tid < 64) {
    float ss = 0.f;
    #pragma unroll
    for (int c = 0; c < 16; ++c) { float xx = v[tid * 16 + c]; ss = fmaf(xx, xx, ss); }
    rn[tid] = fmaxf(sqrtf(ss), 1e-12f);
  }
  __syncthreads();
  float gs = 0.f;
  for (int i = tid; i < 1024; i += 512) {
    float nv = v[i] / rn[i >> 4];
    v[i] = nv;
    gs = fmaf(nv, nv, gs);
  }
  #pragma unroll
  for (int o = 32; o > 0; o >>= 1) gs += __shfl_down(gs, o);
  int wv = tid >> 6, lane = tid & 63;
  if (lane == 0) red[wv] = gs;
  __syncthreads();
  if (tid == 0) {
    float tot = 0.f;
    #pragma unroll
    for (int qq = 0; qq < 8; ++qq) tot += red[qq];
    red[8] = 1.0f / fmaxf(sqrtf(tot), 1e-12f);
  }
  __syncthreads();
  float invg = red[8];
  float acc = 0.f;
  const float4* fw4 = (const float4*)(fcw + tid * 1024);
  const float4* v4  = (const float4*)v;
  #pragma unroll 4
  for (int i = 0; i < 256; ++i) {
    float4 a = fw4[i]; float4 xx = v4[i];
    acc = fmaf(a.x, xx.x, acc); acc = fmaf(a.y, xx.y, acc);
    acc = fmaf(a.z, xx.z, acc); acc = fmaf(a.w, xx.w, acc);
  }
  feat[tid] = fmaf(invg, acc, fcb[tid]);
}

// K5: U[t] = hid_w[:, :300] @ cap0[t] + hid_b. grid 63x512.
__global__ __launch_bounds__(512) void k_U(const float* __restrict__ hid_w,
                                           const float* __restrict__ hid_b,
                                           const float* __restrict__ cap,
                                           float* __restrict__ U) {
  int t = blockIdx.x;
  int tid = threadIdx.x;
  __shared__ __align__(16) float csh[304];
  if (tid < 300) csh[tid] = cap[t * 300 + tid];
  if (tid >= 300 && tid < 304) csh[tid] = 0.f;
  __syncthreads();
  float acc = hid_b[tid];
  const float4* w4 = (const float4*)(hid_w + tid * 812);  // 812*4 bytes, 16B aligned
  const float4* c4 = (const float4*)csh;
  #pragma unroll 5
  for (int i = 0; i < 75; ++i) {
    float4 a = w4[i]; float4 xx = c4[i];
    acc = fmaf(a.x, xx.x, acc); acc = fmaf(a.y, xx.y, acc);
    acc = fmaf(a.z, xx.z, acc); acc = fmaf(a.w, xx.w, acc);
  }
  U[t * 512 + tid] = acc;
}

// K6: sequential RNN. 8 blocks x 256 threads; W_h pinned in VGPRs.
// block b: rows [b*64, b*64+64); wave w: cols [w*128, (w+1)*128); lane = row.
__global__ __launch_bounds__(256, 1) void k_rnn(const float* __restrict__ hid_w,
                                                const float* __restrict__ U,
                                                const float* __restrict__ feat,
                                                float* __restrict__ H,
                                                int* __restrict__ bar) {
  const int b = blockIdx.x;
  const int tid = threadIdx.x;
  const int wv = tid >> 6;
  const int lane = tid & 63;
  const int row = b * 64 + lane;
  const int colbase = wv * 128;
  float wreg[128];
  #pragma unroll
  for (int i = 0; i < 128; ++i)
    wreg[i] = hid_w[row * 812 + 300 + colbase + i];
  __shared__ __align__(16) float hsh[512];
  __shared__ float part[4][64];
  for (int t = 0; t < 63; ++t) {
    const float* hsrc = (t == 0) ? feat : (H + (t - 1) * 512);
    #pragma unroll
    for (int i = 0; i < 2; ++i) {
      int j = tid + i * 256;
      hsh[j] = __hip_atomic_load(hsrc + j, __ATOMIC_RELAXED, __HIP_MEMORY_SCOPE_AGENT);
    }
    __syncthreads();
    float acc = 0.0f;
    #pragma unroll
    for (int i = 0; i < 128; i += 4) {
      float4 hv = *(const float4*)(hsh + colbase + i);  // wave-uniform broadcast
      acc = fmaf(wreg[i + 0], hv.x, acc);
      acc = fmaf(wreg[i + 1], hv.y, acc);
      acc = fmaf(wreg[i + 2], hv.z, acc);
      acc = fmaf(wreg[i + 3], hv.w, acc);
    }
    part[wv][lane] = acc;
    __syncthreads();
    if (wv == 0) {
      float pre = part[0][lane] + part[1][lane] + part[2][lane] + part[3][lane]
                + U[t * 512 + row];
      float hn = sigmoidf_(pre);
      __hip_atomic_store(H + t * 512 + row, hn, __ATOMIC_RELEASE,
                         __HIP_MEMORY_SCOPE_AGENT);
    }
    __syncthreads();
    if (t < 62) {
      if (tid == 0) {
        __threadfence();  // wave0 issued all 64 row stores; drain to MALL
        __hip_atomic_fetch_add(bar + t, 1, __ATOMIC_ACQ_REL,
                               __HIP_MEMORY_SCOPE_AGENT);
        while (__hip_atomic_load(bar + t, __ATOMIC_ACQUIRE,
                                 __HIP_MEMORY_SCOPE_AGENT) < 8) {
          __builtin_amdgcn_s_sleep(1);
        }
      }
      __syncthreads();
    }
  }
}

// K7: y_t = sigmoid(out_w @ h_t + out_b); accumulate squared error. grid 63x512.
__global__ __launch_bounds__(512) void k_loss(const float* __restrict__ outw,
                                              const float* __restrict__ outb,
                                              const float* __restrict__ H,
                                              const float* __restrict__ cap,
                                              float* __restrict__ loss) {
  int t = blockIdx.x;
  int tid = threadIdx.x;
  __shared__ __align__(16) float hsh[512];
  __shared__ float red[8];
  hsh[tid] = H[t * 512 + tid];
  __syncthreads();
  float se = 0.f;
  if (tid < 300) {
    float acc = outb[tid];
    const float4* w4 = (const float4*)(outw + tid * 512);
    const float4* h4 = (const float4*)hsh;
    #pragma unroll 4
    for (int i = 0; i < 128; ++i) {
      float4 a = w4[i]; float4 xx = h4[i];
      acc = fmaf(a.x, xx.x, acc); acc = fmaf(a.y, xx.y, acc);
      acc = fmaf(a.z, xx.z, acc); acc = fmaf(a.w, xx.w, acc);
    }
    float y = sigmoidf_(acc);
    float d = y - cap[(t + 1) * 300 + tid];
    se = d * d;
  }
  #pragma unroll
  for (int o = 32; o > 0; o >>= 1) se += __shfl_down(se, o);
  if ((tid & 63) == 0) red[tid >> 6] = se;
  __syncthreads();
  if (tid == 0) {
    float tot = 0.f;
    #pragma unroll
    for (int qq = 0; qq < 8; ++qq) tot += red[qq];
    atomicAdd(loss, tot * (1.0f / 19200.0f));
  }
}

extern "C" void kernel_launch(void* const* d_in, const int* in_sizes, int n_in,
                              void* d_out, int out_size, void* d_ws, size_t ws_size,
                              hipStream_t stream) {
  (void)in_sizes; (void)n_in; (void)out_size; (void)ws_size;
  const float* img  = (const float*)d_in[0];   // sample 0 only
  const float* cap  = (const float*)d_in[1];   // sample 0 only
  const float* c1w  = (const float*)d_in[2];
  const float* c1b  = (const float*)d_in[3];
  const float* c2w  = (const float*)d_in[4];
  const float* c2b  = (const float*)d_in[5];
  const float* cent = (const float*)d_in[6];
  const float* nvw  = (const float*)d_in[7];
  const float* nvb  = (const float*)d_in[8];
  const float* fcw  = (const float*)d_in[9];
  const float* fcb  = (const float*)d_in[10];
  const float* hidw = (const float*)d_in[11];
  const float* hidb = (const float*)d_in[12];
  const float* outw = (const float*)d_in[13];
  const float* outb = (const float*)d_in[14];

  float* ws   = (float*)d_ws;
  float* p1   = ws;               // 262144
  float* xf   = ws + 262144;      // 262144
  float* vacc = ws + 524288;      // 1024
  float* asum = ws + 525312;      // 64
  float* feat = ws + 525376;      // 512
  float* U    = ws + 525888;      // 63*512 = 32256
  float* H    = ws + 558144;      // 63*512 = 32256
  int*   bar  = (int*)(ws + 590400); // 64 ints

  hipMemsetAsync(vacc, 0, (1024 + 64) * sizeof(float), stream);  // vacc + asum
  hipMemsetAsync(bar, 0, 64 * sizeof(int), stream);
  hipMemsetAsync(d_out, 0, sizeof(float), stream);

  k_conv1<<<1024, 256, 0, stream>>>(img, c1w, c1b, p1);
  k_conv2<<<1024, 256, 0, stream>>>(p1, c2w, c2b, xf);
  k_netvlad<<<64, 256, 0, stream>>>(xf, nvw, nvb, vacc, asum);
  k_vlad_fc<<<1, 512, 0, stream>>>(vacc, asum, cent, fcw, fcb, feat);
  k_U<<<63, 512, 0, stream>>>(hidw, hidb, cap, U);
  k_rnn<<<8, 256, 0, stream>>>(hidw, U, feat, H, bar);
  k_loss<<<63, 512, 0, stream>>>(outw, outb, H, cap, (float*)d_out);
}

// Round 2
// 296.188 us; speedup vs baseline: 1.3621x; 1.3621x over previous
//
#include <hip/hip_runtime.h>
#include <math.h>

// ---------------------------------------------------------------------------
// Only sample 0 of the batch affects the loss (features[0], cap[0]).
//   K1 conv1(3->4)+relu+pool          : img0 -> p1[4][256][256]
//   K2 conv2(4->16)+relu+pool fused with NetVLAD softmax+accumulate
//                                     -> vacc[64][16], asum[64]   (atomics)
//   K3 grid 71: blocks 0..62 : U[t] = hid_w[:, :300] @ cap0[t] + hid_b
//               blocks 63..70: normalize vlad (redundant per block) + FC slice
//                                     -> feat[512]
//   K4 sequential RNN, 8 blocks, W_h in regs; DATA-AS-FLAG sync: H is
//      pre-poisoned 0xAA; sigmoid outputs can never be 0xAAAAAAAA, so
//      consumers poll H cells directly with relaxed agent (sc0/sc1) loads.
//      No counters, no fences, no buffer_inv/wbl2 on the critical path.
//   K5 y_t = sigmoid(out_w @ h_t + out_b); loss = mean((out-cap0)^2)
// ---------------------------------------------------------------------------

#define HPOISON 0xAAAAAAAAu

__device__ __forceinline__ float sigmoidf_(float x) {
  return 1.0f / (1.0f + __expf(-x));
}

// K1: conv1 + relu + avgpool2. grid 1024x256, one thread per pooled output.
__global__ __launch_bounds__(256) void k_conv1(const float* __restrict__ img,
                                               const float* __restrict__ w,
                                               const float* __restrict__ b,
                                               float* __restrict__ p1) {
  int idx = blockIdx.x * 256 + threadIdx.x;
  int ox = idx & 255;
  int oy = (idx >> 8) & 255;
  int c  = idx >> 16;                 // block-uniform (65536 per channel)
  __shared__ float wsh[27];
  __shared__ float bsh;
  if (threadIdx.x < 27) wsh[threadIdx.x] = w[c * 27 + threadIdx.x];
  if (threadIdx.x == 0) bsh = b[c];
  __syncthreads();
  int y0 = oy * 2 - 1, x0 = ox * 2 - 1;
  float a00, a01, a10, a11;
  a00 = a01 = a10 = a11 = bsh;
  #pragma unroll
  for (int ci = 0; ci < 3; ++ci) {
    float P[4][4];
    #pragma unroll
    for (int j = 0; j < 4; ++j) {
      int y = y0 + j;
      #pragma unroll
      for (int i = 0; i < 4; ++i) {
        int x = x0 + i;
        bool ok = ((unsigned)y < 512u) && ((unsigned)x < 512u);
        P[j][i] = ok ? img[ci * 262144 + y * 512 + x] : 0.0f;
      }
    }
    #pragma unroll
    for (int ky = 0; ky < 3; ++ky) {
      #pragma unroll
      for (int kx = 0; kx < 3; ++kx) {
        float wv = wsh[ci * 9 + ky * 3 + kx];
        a00 = fmaf(wv, P[ky][kx],         a00);
        a01 = fmaf(wv, P[ky][kx + 1],     a01);
        a10 = fmaf(wv, P[ky + 1][kx],     a10);
        a11 = fmaf(wv, P[ky + 1][kx + 1], a11);
      }
    }
  }
  p1[idx] = 0.25f * (fmaxf(a00, 0.f) + fmaxf(a01, 0.f) +
                     fmaxf(a10, 0.f) + fmaxf(a11, 0.f));
}

// K2: conv2+relu+pool fused with NetVLAD. grid 64x256; thread = 1 hw pos of
// the 128x128 pooled map; computes its own x[16] then softmax+accumulate.
#define PS_STRIDE 65
#define XS_STRIDE 20
__global__ __launch_bounds__(256, 1) void k_conv2vlad(const float* __restrict__ p1,
                                                      const float* __restrict__ w2,
                                                      const float* __restrict__ b2,
                                                      const float* __restrict__ nvw,
                                                      const float* __restrict__ nvb,
                                                      float* __restrict__ vacc,
                                                      float* __restrict__ asum) {
  __shared__ __align__(16) float ps[128 * PS_STRIDE];  // 33.3 KB
  __shared__ __align__(16) float xs[128 * XS_STRIDE];  // 10.2 KB
  __shared__ float wsh[1024];   // nv weights
  __shared__ float bsh[64];
  __shared__ float aS[256];
  __shared__ float cw[576];     // conv2 weights [16][4][9]
  __shared__ float cb[16];
  int tid = threadIdx.x;
  for (int i = tid; i < 1024; i += 256) wsh[i] = nvw[i];
  if (tid < 64) bsh[tid] = nvb[tid];
  for (int i = tid; i < 576; i += 256) cw[i] = w2[i];
  if (tid < 16) cb[tid] = b2[tid];
  __syncthreads();

  // ---- conv2 + relu + pool for this hw position ----
  int ox = tid & 127;
  int oyl = tid >> 7;                 // 0 or 1
  int oy = blockIdx.x * 2 + oyl;      // 0..127
  int y0 = oy * 2 - 1, x0 = ox * 2 - 1;
  float a[16][4];
  #pragma unroll
  for (int oc = 0; oc < 16; ++oc) {
    float bb = cb[oc];
    a[oc][0] = bb; a[oc][1] = bb; a[oc][2] = bb; a[oc][3] = bb;
  }
  #pragma unroll
  for (int ci = 0; ci < 4; ++ci) {
    float P[4][4];
    #pragma unroll
    for (int j = 0; j < 4; ++j) {
      int y = y0 + j;
      #pragma unroll
      for (int i = 0; i < 4; ++i) {
        int x = x0 + i;
        bool ok = ((unsigned)y < 256u) && ((unsigned)x < 256u);
        P[j][i] = ok ? p1[ci * 65536 + y * 256 + x] : 0.0f;
      }
    }
    #pragma unroll
    for (int oc = 0; oc < 16; ++oc) {
      #pragma unroll
      for (int ky = 0; ky < 3; ++ky) {
        #pragma unroll
        for (int kx = 0; kx < 3; ++kx) {
          float wv = cw[oc * 36 + ci * 9 + ky * 3 + kx];
          a[oc][0] = fmaf(wv, P[ky][kx],         a[oc][0]);
          a[oc][1] = fmaf(wv, P[ky][kx + 1],     a[oc][1]);
          a[oc][2] = fmaf(wv, P[ky + 1][kx],     a[oc][2]);
          a[oc][3] = fmaf(wv, P[ky + 1][kx + 1], a[oc][3]);
        }
      }
    }
  }
  float x[16];
  #pragma unroll
  for (int oc = 0; oc < 16; ++oc)
    x[oc] = 0.25f * (fmaxf(a[oc][0], 0.f) + fmaxf(a[oc][1], 0.f) +
                     fmaxf(a[oc][2], 0.f) + fmaxf(a[oc][3], 0.f));

  // ---- NetVLAD: logits + softmax over 64 clusters ----
  float p[64];
  float m = -1e30f;
  #pragma unroll
  for (int k = 0; k < 64; ++k) {
    float acc = bsh[k];
    #pragma unroll
    for (int c = 0; c < 16; ++c) acc = fmaf(wsh[k * 16 + c], x[c], acc);
    p[k] = acc;
    m = fmaxf(m, acc);
  }
  float s = 0.f;
  #pragma unroll
  for (int k = 0; k < 64; ++k) { p[k] = __expf(p[k] - m); s += p[k]; }
  float inv = 1.0f / s;
  #pragma unroll
  for (int k = 0; k < 64; ++k) p[k] *= inv;

  int q = tid >> 6, k = tid & 63;
  float acc[16];
  #pragma unroll
  for (int c = 0; c < 16; ++c) acc[c] = 0.f;
  float accA = 0.f;

  for (int pass = 0; pass < 2; ++pass) {
    __syncthreads();
    if ((tid >> 7) == pass) {
      int tt = tid & 127;
      #pragma unroll
      for (int kk = 0; kk < 64; ++kk) ps[tt * PS_STRIDE + kk] = p[kk];
      #pragma unroll
      for (int c = 0; c < 16; ++c) xs[tt * XS_STRIDE + c] = x[c];
    }
    __syncthreads();
    #pragma unroll
    for (int j = 0; j < 32; ++j) {
      int tt = q * 32 + j;
      float pv = ps[tt * PS_STRIDE + k];
      accA += pv;
      const float4* xv = (const float4*)(xs + tt * XS_STRIDE);
      #pragma unroll
      for (int c4 = 0; c4 < 4; ++c4) {
        float4 xx = xv[c4];
        acc[c4 * 4 + 0] = fmaf(pv, xx.x, acc[c4 * 4 + 0]);
        acc[c4 * 4 + 1] = fmaf(pv, xx.y, acc[c4 * 4 + 1]);
        acc[c4 * 4 + 2] = fmaf(pv, xx.z, acc[c4 * 4 + 2]);
        acc[c4 * 4 + 3] = fmaf(pv, xx.w, acc[c4 * 4 + 3]);
      }
    }
  }
  __syncthreads();
  float* red = ps;   // reuse as [256][16]
  #pragma unroll
  for (int c = 0; c < 16; ++c) red[tid * 16 + c] = acc[c];
  aS[tid] = accA;
  __syncthreads();
  if (q == 0) {
    float aa = aS[k] + aS[64 + k] + aS[128 + k] + aS[192 + k];
    atomicAdd(&asum[k], aa);
  }
  int k2 = tid >> 2;
  int cg = (tid & 3) * 4;
  #pragma unroll
  for (int cc = 0; cc < 4; ++cc) {
    int c = cg + cc;
    float v = red[(0 * 64 + k2) * 16 + c] + red[(1 * 64 + k2) * 16 + c] +
              red[(2 * 64 + k2) * 16 + c] + red[(3 * 64 + k2) * 16 + c];
    atomicAdd(&vacc[k2 * 16 + c], v);
  }
}

// K3: grid 71 x 512. Blocks 0..62: U[t]. Blocks 63..70: vlad-normalize + FC.
__global__ __launch_bounds__(512) void k_featU(const float* __restrict__ hid_w,
                                               const float* __restrict__ hid_b,
                                               const float* __restrict__ cap,
                                               const float* __restrict__ vacc,
                                               const float* __restrict__ asum,
                                               const float* __restrict__ cent,
                                               const float* __restrict__ fcw,
                                               const float* __restrict__ fcb,
                                               float* __restrict__ U,
                                               float* __restrict__ feat) {
  int tid = threadIdx.x;
  if (blockIdx.x < 63) {
    int t = blockIdx.x;
    __shared__ __align__(16) float csh[300];
    if (tid < 300) csh[tid] = cap[t * 300 + tid];
    __syncthreads();
    float acc = hid_b[tid];
    const float4* w4 = (const float4*)(hid_w + tid * 812);
    const float4* c4 = (const float4*)csh;
    #pragma unroll 5
    for (int i = 0; i < 75; ++i) {
      float4 aa = w4[i]; float4 xx = c4[i];
      acc = fmaf(aa.x, xx.x, acc); acc = fmaf(aa.y, xx.y, acc);
      acc = fmaf(aa.z, xx.z, acc); acc = fmaf(aa.w, xx.w, acc);
    }
    U[t * 512 + tid] = acc;
    return;
  }
  // FC slice: block q handles feat rows [q*64, q*64+64)
  int q = blockIdx.x - 63;
  __shared__ __align__(16) float v[1024];
  __shared__ float rn[64];
  __shared__ float red[9];
  for (int i = tid; i < 1024; i += 512)
    v[i] = vacc[i] - asum[i >> 4] * cent[i];
  __syncthreads();
  if (tid < 64) {
    float ss = 0.f;
    #pragma unroll
    for (int c = 0; c < 16; ++c) { float xx = v[tid * 16 + c]; ss = fmaf(xx, xx, ss); }
    rn[tid] = fmaxf(sqrtf(ss), 1e-12f);
  }
  __syncthreads();
  float gs = 0.f;
  for (int i = tid; i < 1024; i += 512) {
    float nv = v[i] / rn[i >> 4];
    v[i] = nv;
    gs = fmaf(nv, nv, gs);
  }
  #pragma unroll
  for (int o = 32; o > 0; o >>= 1) gs += __shfl_down(gs, o);
  int wv = tid >> 6, lane = tid & 63;
  if (lane == 0) red[wv] = gs;
  __syncthreads();
  if (tid == 0) {
    float tot = 0.f;
    #pragma unroll
    for (int qq = 0; qq < 8; ++qq) tot += red[qq];
    red[8] = 1.0f / fmaxf(sqrtf(tot), 1e-12f);
  }
  __syncthreads();
  float invg = red[8];
  // row r = q*64 + (tid>>3); 8 threads per row, chunk = (tid&7)*128 floats
  int r = q * 64 + (tid >> 3);
  int cch = tid & 7;
  float acc = 0.f;
  const float4* fw4 = (const float4*)(fcw + r * 1024 + cch * 128);
  const float4* v4  = (const float4*)(v + cch * 128);
  #pragma unroll 4
  for (int i = 0; i < 32; ++i) {
    float4 aa = fw4[i]; float4 xx = v4[i];
    acc = fmaf(aa.x, xx.x, acc); acc = fmaf(aa.y, xx.y, acc);
    acc = fmaf(aa.z, xx.z, acc); acc = fmaf(aa.w, xx.w, acc);
  }
  acc += __shfl_down(acc, 4, 8);
  acc += __shfl_down(acc, 2, 8);
  acc += __shfl_down(acc, 1, 8);
  if (cch == 0) feat[r] = fmaf(invg, acc, fcb[r]);
}

// K4: sequential RNN. 8 blocks x 256; W_h pinned in regs; data-as-flag sync.
// wave wv covers cols [wv*128,(wv+1)*128); lane = row within block's 64 rows.
__global__ __launch_bounds__(256, 1) void k_rnn(const float* __restrict__ hid_w,
                                                const float* __restrict__ U,
                                                const float* __restrict__ feat,
                                                float* __restrict__ H) {
  const int b = blockIdx.x;
  const int tid = threadIdx.x;
  const int wv = tid >> 6;
  const int lane = tid & 63;
  const int row = b * 64 + lane;
  const int colbase = wv * 128;
  float4 wr[32];
  const float4* wp = (const float4*)(hid_w + row * 812 + 300 + colbase);
  #pragma unroll
  for (int i = 0; i < 32; ++i) wr[i] = wp[i];
  __shared__ __align__(16) float hsh[512];
  __shared__ float part[4][64];
  unsigned int* Hu = (unsigned int*)H;
  for (int t = 0; t < 63; ++t) {
    float uval = (wv == 0) ? U[t * 512 + row] : 0.f;
    if (t == 0) {
      hsh[tid] = feat[tid];
      hsh[tid + 256] = feat[tid + 256];
    } else {
      const unsigned int* src = Hu + (t - 1) * 512;
      unsigned int a0, a1;
      do {
        a0 = __hip_atomic_load(src + tid, __ATOMIC_RELAXED,
                               __HIP_MEMORY_SCOPE_AGENT);
      } while (a0 == HPOISON);
      do {
        a1 = __hip_atomic_load(src + tid + 256, __ATOMIC_RELAXED,
                               __HIP_MEMORY_SCOPE_AGENT);
      } while (a1 == HPOISON);
      hsh[tid] = __uint_as_float(a0);
      hsh[tid + 256] = __uint_as_float(a1);
    }
    __syncthreads();                       // hsh staged; part[t-1] fully read
    float acc = 0.0f;
    #pragma unroll
    for (int i = 0; i < 32; ++i) {
      float4 hv = *(const float4*)(hsh + colbase + i * 4);  // wave-uniform
      acc = fmaf(wr[i].x, hv.x, acc);
      acc = fmaf(wr[i].y, hv.y, acc);
      acc = fmaf(wr[i].z, hv.z, acc);
      acc = fmaf(wr[i].w, hv.w, acc);
    }
    part[wv][lane] = acc;
    __syncthreads();                       // parts ready
    if (wv == 0) {
      float pre = part[0][lane] + part[1][lane] + part[2][lane] +
                  part[3][lane] + uval;
      float hn = sigmoidf_(pre);
      __hip_atomic_store(Hu + t * 512 + row, __float_as_uint(hn),
                         __ATOMIC_RELAXED, __HIP_MEMORY_SCOPE_AGENT);
    }
    // no barrier: consumers poll the cells themselves (data-as-flag)
  }
}

// K5: y_t = sigmoid(out_w @ h_t + out_b); accumulate squared error. grid 63x512.
__global__ __launch_bounds__(512) void k_loss(const float* __restrict__ outw,
                                              const float* __restrict__ outb,
                                              const float* __restrict__ H,
                                              const float* __restrict__ cap,
                                              float* __restrict__ loss) {
  int t = blockIdx.x;
  int tid = threadIdx.x;
  __shared__ __align__(16) float hsh[512];
  __shared__ float red[8];
  hsh[tid] = H[t * 512 + tid];
  __syncthreads();
  float se = 0.f;
  if (tid < 300) {
    float acc = outb[tid];
    const float4* w4 = (const float4*)(outw + tid * 512);
    const float4* h4 = (const float4*)hsh;
    #pragma unroll 4
    for (int i = 0; i < 128; ++i) {
      float4 aa = w4[i]; float4 xx = h4[i];
      acc = fmaf(aa.x, xx.x, acc); acc = fmaf(aa.y, xx.y, acc);
      acc = fmaf(aa.z, xx.z, acc); acc = fmaf(aa.w, xx.w, acc);
    }
    float y = sigmoidf_(acc);
    float d = y - cap[(t + 1) * 300 + tid];
    se = d * d;
  }
  #pragma unroll
  for (int o = 32; o > 0; o >>= 1) se += __shfl_down(se, o);
  if ((tid & 63) == 0) red[tid >> 6] = se;
  __syncthreads();
  if (tid == 0) {
    float tot = 0.f;
    #pragma unroll
    for (int qq = 0; qq < 8; ++qq) tot += red[qq];
    atomicAdd(loss, tot * (1.0f / 19200.0f));
  }
}

extern "C" void kernel_launch(void* const* d_in, const int* in_sizes, int n_in,
                              void* d_out, int out_size, void* d_ws, size_t ws_size,
                              hipStream_t stream) {
  (void)in_sizes; (void)n_in; (void)out_size; (void)ws_size;
  const float* img  = (const float*)d_in[0];   // sample 0 only
  const float* cap  = (const float*)d_in[1];   // sample 0 only
  const float* c1w  = (const float*)d_in[2];
  const float* c1b  = (const float*)d_in[3];
  const float* c2w  = (const float*)d_in[4];
  const float* c2b  = (const float*)d_in[5];
  const float* cent = (const float*)d_in[6];
  const float* nvw  = (const float*)d_in[7];
  const float* nvb  = (const float*)d_in[8];
  const float* fcw  = (const float*)d_in[9];
  const float* fcb  = (const float*)d_in[10];
  const float* hidw = (const float*)d_in[11];
  const float* hidb = (const float*)d_in[12];
  const float* outw = (const float*)d_in[13];
  const float* outb = (const float*)d_in[14];

  float* ws   = (float*)d_ws;
  float* p1   = ws;               // 262144
  float* vacc = ws + 262144;      // 1024
  float* asum = ws + 263168;      // 64
  float* feat = ws + 263232;      // 512
  float* U    = ws + 263744;      // 63*512 = 32256
  float* H    = ws + 296000;      // 63*512 = 32256

  hipMemsetAsync(vacc, 0, (1024 + 64) * sizeof(float), stream);
  hipMemsetAsync(H, 0xAA, 63 * 512 * sizeof(float), stream);  // data-as-flag
  hipMemsetAsync(d_out, 0, sizeof(float), stream);

  k_conv1<<<1024, 256, 0, stream>>>(img, c1w, c1b, p1);
  k_conv2vlad<<<64, 256, 0, stream>>>(p1, c2w, c2b, nvw, nvb, vacc, asum);
  k_featU<<<71, 512, 0, stream>>>(hidw, hidb, cap, vacc, asum, cent,
                                  fcw, fcb, U, feat);
  k_rnn<<<8, 256, 0, stream>>>(hidw, U, feat, H);
  k_loss<<<63, 512, 0, stream>>>(outw, outb, H, cap, (float*)d_out);
}